// Round 1
// baseline (3279.268 us; speedup 1.0000x reference)
//
#include <hip/hip_runtime.h>
#include <hip/hip_bf16.h>

#define B_SZ 16
#define IN_C 64
#define OUT_C 64
#define STYLE_DIM 512
#define HW 16384          // 128*128
#define EPS 1e-8f

// ---------------------------------------------------------------------------
// Kernel 1: compute per-sample modulated+demodulated weight W[b][o][i]
//   s[b][i]   = dot(style[b], geo_w[i]) + geo_b[i]
//   mod[b][i] = s + 1
//   w         = weight[o][i] * mod[b][i]
//   demod[b][o] = rsqrt(sum_i w^2 + eps)
//   W[b][o][i]  = w * demod
// Grid: 16 blocks (one per sample) x 256 threads.
// ---------------------------------------------------------------------------
__global__ __launch_bounds__(256) void modw_kernel(
    const float* __restrict__ style,   // (B, STYLE_DIM)
    const float* __restrict__ weight,  // (OUT_C, IN_C)
    const float* __restrict__ geo_w,   // (IN_C, STYLE_DIM)
    const float* __restrict__ geo_b,   // (IN_C)
    float* __restrict__ Wout)          // (B, OUT_C, IN_C)
{
    const int b = blockIdx.x;
    __shared__ float smod[IN_C];

    // 4 threads per in-channel, each covers 128 of the 512-dim dot
    const int i    = threadIdx.x >> 2;
    const int part = threadIdx.x & 3;
    const float* st = style + b * STYLE_DIM;
    const float* gw = geo_w + i * STYLE_DIM;

    float sum = 0.0f;
    const int k0 = part * 128;
    #pragma unroll 8
    for (int k = 0; k < 128; ++k) sum += st[k0 + k] * gw[k0 + k];
    // reduce the 4-lane group (lanes within a wave)
    sum += __shfl_xor(sum, 1);
    sum += __shfl_xor(sum, 2);
    if (part == 0) smod[i] = sum + geo_b[i] + 1.0f;
    __syncthreads();

    if (threadIdx.x < OUT_C) {
        const int o = threadIdx.x;
        float wrow[IN_C];
        float d = 0.0f;
        #pragma unroll
        for (int ii = 0; ii < IN_C; ++ii) {
            float wv = weight[o * IN_C + ii] * smod[ii];
            wrow[ii] = wv;
            d += wv * wv;
        }
        d = rsqrtf(d + EPS);
        float* Wo = Wout + (b * OUT_C + o) * IN_C;
        #pragma unroll
        for (int ii = 0; ii < IN_C; ++ii) Wo[ii] = wrow[ii] * d;
    }
}

// ---------------------------------------------------------------------------
// Kernel 2: out[b][o][hw] = sum_i W[b][o][i] * x[b][i][hw] + bias[o]
// One thread per (b, hw). 64 f32 accumulators per thread.
// W[b] (16 KB) staged in LDS; all lanes read the same W element per FMA
// (broadcast, conflict-free). x reads / out writes fully coalesced.
// Grid: B * HW / 256 = 1024 blocks, 64 blocks per sample.
// ---------------------------------------------------------------------------
__global__ __launch_bounds__(256, 4) void conv_kernel(
    const float* __restrict__ x,     // (B, IN_C, HW)
    const float* __restrict__ W,     // (B, OUT_C, IN_C)
    const float* __restrict__ bias,  // (OUT_C)
    float* __restrict__ out)         // (B, OUT_C, HW)
{
    __shared__ float sW[OUT_C * IN_C];   // 16 KB
    __shared__ float sB[OUT_C];

    const int b  = blockIdx.x >> 6;            // 64 blocks per sample
    const int hw = ((blockIdx.x & 63) << 8) + threadIdx.x;

    const float* Wb = W + b * OUT_C * IN_C;
    #pragma unroll
    for (int k = threadIdx.x; k < OUT_C * IN_C; k += 256) sW[k] = Wb[k];
    if (threadIdx.x < OUT_C) sB[threadIdx.x] = bias[threadIdx.x];
    __syncthreads();

    const float* xb = x + (size_t)b * IN_C * HW + hw;

    float acc[OUT_C];
    #pragma unroll
    for (int o = 0; o < OUT_C; ++o) acc[o] = 0.0f;

    #pragma unroll 4
    for (int i = 0; i < IN_C; ++i) {
        const float xv = xb[(size_t)i * HW];
        #pragma unroll
        for (int o = 0; o < OUT_C; ++o)
            acc[o] = fmaf(sW[o * IN_C + i], xv, acc[o]);
    }

    float* ob = out + (size_t)b * OUT_C * HW + hw;
    #pragma unroll
    for (int o = 0; o < OUT_C; ++o)
        ob[(size_t)o * HW] = acc[o] + sB[o];
}

extern "C" void kernel_launch(void* const* d_in, const int* in_sizes, int n_in,
                              void* d_out, int out_size, void* d_ws, size_t ws_size,
                              hipStream_t stream) {
    const float* x      = (const float*)d_in[0];  // (16,64,128,128)
    const float* style  = (const float*)d_in[1];  // (16,512)
    const float* weight = (const float*)d_in[2];  // (1,64,64,1,1)
    const float* bias   = (const float*)d_in[3];  // (1,64)
    const float* geo_w  = (const float*)d_in[4];  // (64,512)
    const float* geo_b  = (const float*)d_in[5];  // (64)
    float* out = (float*)d_out;
    float* Wmod = (float*)d_ws;                   // 16*64*64*4 = 64 KB

    modw_kernel<<<B_SZ, 256, 0, stream>>>(style, weight, geo_w, geo_b, Wmod);
    conv_kernel<<<(B_SZ * HW) / 256, 256, 0, stream>>>(x, Wmod, bias, out);
}

// Round 6
// 243.892 us; speedup vs baseline: 13.4456x; 13.4456x over previous
//
#include <hip/hip_runtime.h>
#include <hip/hip_bf16.h>

#define B_SZ 16
#define IN_C 64
#define OUT_C 64
#define STYLE_DIM 512
#define HW 16384          // 128*128
#define EPS 1e-8f

// ---------------------------------------------------------------------------
// Kernel 1: per-sample modulated+demodulated weight W[b][o][i]
// Grid: 16 blocks (one per sample) x 256 threads. Tiny (64 KB output).
// ---------------------------------------------------------------------------
__global__ __launch_bounds__(256) void modw_kernel(
    const float* __restrict__ style,   // (B, STYLE_DIM)
    const float* __restrict__ weight,  // (OUT_C, IN_C)
    const float* __restrict__ geo_w,   // (IN_C, STYLE_DIM)
    const float* __restrict__ geo_b,   // (IN_C)
    float* __restrict__ Wout)          // (B, OUT_C, IN_C)
{
    const int b = blockIdx.x;
    __shared__ float smod[IN_C];

    // 4 threads per in-channel, each covers 128 of the 512-dim dot
    const int i    = threadIdx.x >> 2;
    const int part = threadIdx.x & 3;
    const float* st = style + b * STYLE_DIM;
    const float* gw = geo_w + i * STYLE_DIM;

    float sum = 0.0f;
    const int k0 = part * 128;
    #pragma unroll 8
    for (int k = 0; k < 128; ++k) sum += st[k0 + k] * gw[k0 + k];
    sum += __shfl_xor(sum, 1);
    sum += __shfl_xor(sum, 2);
    if (part == 0) smod[i] = sum + geo_b[i] + 1.0f;
    __syncthreads();

    if (threadIdx.x < OUT_C) {
        const int o = threadIdx.x;
        float wrow[IN_C];
        float d = 0.0f;
        #pragma unroll
        for (int ii = 0; ii < IN_C; ++ii) {
            float wv = weight[o * IN_C + ii] * smod[ii];
            wrow[ii] = wv;
            d += wv * wv;
        }
        d = rsqrtf(d + EPS);
        float* Wo = Wout + (b * OUT_C + o) * IN_C;
        #pragma unroll
        for (int ii = 0; ii < IN_C; ++ii) Wo[ii] = wrow[ii] * d;
    }
}

// ---------------------------------------------------------------------------
// Kernel 2: out[b][o][hw] = sum_i W[b][o][i] * x[b][i][hw] + bias[o]
// 512 threads/block: group 0 (tid<256) does out-channels [0,32),
// group 1 does [32,64), both over the same 256 hw positions. Each thread
// keeps 32 f32 accumulators (~45 VGPR -> no spill, 8 waves/SIMD).
// Both groups load identical x addresses simultaneously -> L1 broadcast,
// so HBM x traffic stays 1x. All global accesses coalesced dwords.
// Grid: B * HW / 256 = 1024 blocks.
// ---------------------------------------------------------------------------
__global__ __launch_bounds__(512) void conv_kernel(
    const float* __restrict__ x,     // (B, IN_C, HW)
    const float* __restrict__ W,     // (B, OUT_C, IN_C)
    const float* __restrict__ bias,  // (OUT_C)
    float* __restrict__ out)         // (B, OUT_C, HW)
{
    __shared__ float sW[OUT_C * IN_C];   // 16 KB

    const int b  = blockIdx.x >> 6;                       // 64 blocks/sample
    const int hw = ((blockIdx.x & 63) << 8) + (threadIdx.x & 255);
    const int og = (threadIdx.x >> 8) << 5;               // 0 or 32

    const float* Wb = W + b * OUT_C * IN_C;
    for (int k = threadIdx.x; k < OUT_C * IN_C; k += 512) sW[k] = Wb[k];
    __syncthreads();

    const float* xb = x + (size_t)b * IN_C * HW + hw;

    float acc[32];
    #pragma unroll
    for (int o = 0; o < 32; ++o) acc[o] = 0.0f;

    #pragma unroll 8
    for (int i = 0; i < IN_C; ++i) {
        const float xv = xb[(size_t)i * HW];
        const float* sWi = sW + og * IN_C + i;
        #pragma unroll
        for (int o = 0; o < 32; ++o)
            acc[o] = fmaf(sWi[o * IN_C], xv, acc[o]);
    }

    float* ob = out + ((size_t)b * OUT_C + og) * HW + hw;
    #pragma unroll
    for (int o = 0; o < 32; ++o)
        ob[(size_t)o * HW] = acc[o] + bias[og + o];
}

extern "C" void kernel_launch(void* const* d_in, const int* in_sizes, int n_in,
                              void* d_out, int out_size, void* d_ws, size_t ws_size,
                              hipStream_t stream) {
    const float* x      = (const float*)d_in[0];  // (16,64,128,128)
    const float* style  = (const float*)d_in[1];  // (16,512)
    const float* weight = (const float*)d_in[2];  // (1,64,64,1,1)
    const float* bias   = (const float*)d_in[3];  // (1,64)
    const float* geo_w  = (const float*)d_in[4];  // (64,512)
    const float* geo_b  = (const float*)d_in[5];  // (64)
    float* out = (float*)d_out;
    float* Wmod = (float*)d_ws;                   // 16*64*64*4 = 64 KB

    modw_kernel<<<B_SZ, 256, 0, stream>>>(style, weight, geo_w, geo_b, Wmod);
    conv_kernel<<<(B_SZ * HW) / 256, 512, 0, stream>>>(x, Wmod, bias, out);
}

// Round 7
// 194.055 us; speedup vs baseline: 16.8987x; 1.2568x over previous
//
#include <hip/hip_runtime.h>
#include <hip/hip_bf16.h>

#define B_SZ 16
#define IN_C 64
#define OUT_C 64
#define STYLE_DIM 512
#define HW 16384          // 128*128
#define HWT 512           // hw positions per block
#define EPS 1e-8f

// ---------------------------------------------------------------------------
// Fully fused StyleMod: one kernel, one dispatch.
// Grid: 16 samples x 32 hw-tiles = 512 blocks x 512 threads (2 blocks/CU,
// whole grid resident). Each block redundantly recomputes its sample's
// modulated/demodulated weights (trivial: 32K MACs, geo_w L2-resident),
// stores them TRANSPOSED in LDS (sWT[i][o]) so the main loop reads weights
// as 2x ds_read_b128 per i instead of 32x ds_read_b32 (R6 was LDS-issue
// bound: 2048 b32/wave x 5.8cyc ~= the whole 150us runtime).
// Main loop: each thread = 8 out-channels x 8 hw positions, 64 f32 acc.
// ---------------------------------------------------------------------------
__global__ __launch_bounds__(512) void fused_kernel(
    const float* __restrict__ x,       // (B, IN_C, HW)
    const float* __restrict__ style,   // (B, STYLE_DIM)
    const float* __restrict__ weight,  // (OUT_C, IN_C)
    const float* __restrict__ bias,    // (OUT_C)
    const float* __restrict__ geo_w,   // (IN_C, STYLE_DIM)
    const float* __restrict__ geo_b,   // (IN_C)
    float* __restrict__ out)           // (B, OUT_C, HW)
{
    __shared__ float smod[IN_C];
    __shared__ float sWT[IN_C * OUT_C];   // transposed: [i][o], 16 KB

    const int tid = threadIdx.x;
    const int b   = blockIdx.x >> 5;            // 32 blocks per sample
    const int hwt = (blockIdx.x & 31) * HWT;

    // ---- phase 1: smod[i] = dot(style[b], geo_w[i]) + geo_b[i] + 1
    {
        const int i    = tid >> 3;              // 64 rows
        const int part = tid & 7;               // 8 lanes per row
        const float* st = style + b * STYLE_DIM + part * 64;
        const float* gw = geo_w + i * STYLE_DIM + part * 64;
        float s = 0.0f;
        #pragma unroll
        for (int k = 0; k < 64; ++k) s = fmaf(st[k], gw[k], s);
        s += __shfl_xor(s, 1);
        s += __shfl_xor(s, 2);
        s += __shfl_xor(s, 4);
        if (part == 0) smod[i] = s + geo_b[i] + 1.0f;
    }
    __syncthreads();

    // ---- phase 2: demodulate, write transposed weight tile
    if (tid < OUT_C) {
        const int o = tid;
        const float* wr = weight + o * IN_C;
        float d = 0.0f;
        #pragma unroll
        for (int ii = 0; ii < IN_C; ++ii) {
            const float wv = wr[ii] * smod[ii];
            d = fmaf(wv, wv, d);
        }
        d = rsqrtf(d + EPS);
        #pragma unroll
        for (int ii = 0; ii < IN_C; ++ii)
            sWT[ii * OUT_C + o] = wr[ii] * smod[ii] * d;   // consecutive o -> no conflict
    }
    __syncthreads();

    // ---- phase 3: out[b][o][hw] = sum_i W[o][i] * x[b][i][hw] + bias[o]
    const int obase = (tid >> 6) << 3;          // wave-uniform: 0,8,...,56
    const int hw    = hwt + (tid & 63) * 8;     // 8 consecutive hw per thread

    const float* xb = x + (size_t)b * IN_C * HW + hw;

    float acc[8][8];
    #pragma unroll
    for (int o = 0; o < 8; ++o)
        #pragma unroll
        for (int h = 0; h < 8; ++h) acc[o][h] = 0.0f;

    #pragma unroll 8
    for (int i = 0; i < IN_C; ++i) {
        const float4 xa = *reinterpret_cast<const float4*>(xb + (size_t)i * HW);
        const float4 xc = *reinterpret_cast<const float4*>(xb + (size_t)i * HW + 4);
        const float4 w0 = *reinterpret_cast<const float4*>(&sWT[i * OUT_C + obase]);
        const float4 w1 = *reinterpret_cast<const float4*>(&sWT[i * OUT_C + obase + 4]);
        const float wv[8] = {w0.x, w0.y, w0.z, w0.w, w1.x, w1.y, w1.z, w1.w};
        const float xv[8] = {xa.x, xa.y, xa.z, xa.w, xc.x, xc.y, xc.z, xc.w};
        #pragma unroll
        for (int o = 0; o < 8; ++o)
            #pragma unroll
            for (int h = 0; h < 8; ++h)
                acc[o][h] = fmaf(wv[o], xv[h], acc[o][h]);
    }

    float* ob = out + ((size_t)b * OUT_C + obase) * HW + hw;
    #pragma unroll
    for (int o = 0; o < 8; ++o) {
        const float bv = bias[obase + o];       // wave-uniform -> scalar load
        float4 r0, r1;
        r0.x = acc[o][0] + bv;  r0.y = acc[o][1] + bv;
        r0.z = acc[o][2] + bv;  r0.w = acc[o][3] + bv;
        r1.x = acc[o][4] + bv;  r1.y = acc[o][5] + bv;
        r1.z = acc[o][6] + bv;  r1.w = acc[o][7] + bv;
        *reinterpret_cast<float4*>(ob + (size_t)o * HW)     = r0;
        *reinterpret_cast<float4*>(ob + (size_t)o * HW + 4) = r1;
    }
}

extern "C" void kernel_launch(void* const* d_in, const int* in_sizes, int n_in,
                              void* d_out, int out_size, void* d_ws, size_t ws_size,
                              hipStream_t stream) {
    const float* x      = (const float*)d_in[0];  // (16,64,128,128)
    const float* style  = (const float*)d_in[1];  // (16,512)
    const float* weight = (const float*)d_in[2];  // (1,64,64,1,1)
    const float* bias   = (const float*)d_in[3];  // (1,64)
    const float* geo_w  = (const float*)d_in[4];  // (64,512)
    const float* geo_b  = (const float*)d_in[5];  // (64)
    float* out = (float*)d_out;

    fused_kernel<<<B_SZ * (HW / HWT), 512, 0, stream>>>(
        x, style, weight, bias, geo_w, geo_b, out);
}

// Round 9
// 169.633 us; speedup vs baseline: 19.3315x; 1.1440x over previous
//
#include <hip/hip_runtime.h>
#include <hip/hip_bf16.h>

#define B_SZ 16
#define IN_C 64
#define OUT_C 64
#define STYLE_DIM 512
#define HW 16384          // 128*128
#define HWT 256           // hw positions per block
#define EPS 1e-8f

// ---------------------------------------------------------------------------
// Fully fused StyleMod, one dispatch.
// Grid: 16 samples x 64 hw-tiles = 1024 blocks x 256 threads (4 blocks/CU).
// Phase 1/2: redundant per-block recompute of modulated+demodulated weights
// (32K MACs, geo_w L2-resident), stored transposed sWT[i][o] in LDS.
// Phase 3: thread = 8 out-channels x 8 hw. i-loop processed in PAIRS with
// explicit register double-buffering: next pair's x (4 float4) is issued
// before the current pair's 128 FMAs, hiding the ~450cy L3 latency that made
// R7 latency-bound (VALUBusy 17%, VGPR 72 = loads scheduled just-before-use).
// ---------------------------------------------------------------------------
__global__ __launch_bounds__(256) void fused_kernel(
    const float* __restrict__ x,       // (B, IN_C, HW)
    const float* __restrict__ style,   // (B, STYLE_DIM)
    const float* __restrict__ weight,  // (OUT_C, IN_C)
    const float* __restrict__ bias,    // (OUT_C)
    const float* __restrict__ geo_w,   // (IN_C, STYLE_DIM)
    const float* __restrict__ geo_b,   // (IN_C)
    float* __restrict__ out)           // (B, OUT_C, HW)
{
    __shared__ float smod[IN_C];
    __shared__ float sWT[IN_C * OUT_C];   // transposed [i][o], 16 KB

    const int tid = threadIdx.x;
    const int b   = blockIdx.x >> 6;            // 64 tiles per sample
    const int hwt = (blockIdx.x & 63) * HWT;

    // ---- phase 1: smod[i] = dot(style[b], geo_w[i]) + geo_b[i] + 1
    {
        const int i    = tid >> 2;              // 64 rows
        const int part = tid & 3;               // 4 lanes/row, 128 elems each
        const float4* st4 = reinterpret_cast<const float4*>(style + b * STYLE_DIM + part * 128);
        const float4* gw4 = reinterpret_cast<const float4*>(geo_w + i * STYLE_DIM + part * 128);
        float s = 0.0f;
        #pragma unroll
        for (int k = 0; k < 32; ++k) {
            const float4 a = st4[k];
            const float4 g = gw4[k];
            s = fmaf(a.x, g.x, s); s = fmaf(a.y, g.y, s);
            s = fmaf(a.z, g.z, s); s = fmaf(a.w, g.w, s);
        }
        s += __shfl_xor(s, 1);
        s += __shfl_xor(s, 2);
        if (part == 0) smod[i] = s + geo_b[i] + 1.0f;
    }
    __syncthreads();

    // ---- phase 2: demodulate, write transposed weight tile
    if (tid < OUT_C) {
        const int o = tid;
        const float* wr = weight + o * IN_C;
        float d = 0.0f;
        #pragma unroll
        for (int ii = 0; ii < IN_C; ++ii) {
            const float wv = wr[ii] * smod[ii];
            d = fmaf(wv, wv, d);
        }
        d = rsqrtf(d + EPS);
        #pragma unroll
        for (int ii = 0; ii < IN_C; ++ii)
            sWT[ii * OUT_C + o] = wr[ii] * smod[ii] * d;  // consecutive o -> no conflict
    }
    __syncthreads();

    // ---- phase 3
    const int obase = (tid >> 5) << 3;          // 8 o-groups of 8
    const int hw    = hwt + (tid & 31) * 8;     // 32 hw-groups of 8

    const float* xb = x + (size_t)b * IN_C * HW + hw;

    float acc[8][8];
    #pragma unroll
    for (int o = 0; o < 8; ++o)
        #pragma unroll
        for (int h = 0; h < 8; ++h) acc[o][h] = 0.0f;

#define FMA_TILE(W0, W1, XA, XC) do {                                   \
        const float wv[8] = {(W0).x,(W0).y,(W0).z,(W0).w,               \
                             (W1).x,(W1).y,(W1).z,(W1).w};              \
        const float xv[8] = {(XA).x,(XA).y,(XA).z,(XA).w,               \
                             (XC).x,(XC).y,(XC).z,(XC).w};              \
        _Pragma("unroll")                                               \
        for (int o = 0; o < 8; ++o)                                     \
            _Pragma("unroll")                                           \
            for (int h = 0; h < 8; ++h)                                 \
                acc[o][h] = fmaf(wv[o], xv[h], acc[o][h]);              \
    } while (0)

    // register double-buffer over i-pairs
    float4 ca0 = *reinterpret_cast<const float4*>(xb);
    float4 cc0 = *reinterpret_cast<const float4*>(xb + 4);
    float4 ca1 = *reinterpret_cast<const float4*>(xb + HW);
    float4 cc1 = *reinterpret_cast<const float4*>(xb + HW + 4);

    #pragma unroll
    for (int i = 0; i < IN_C; i += 2) {
        float4 na0 = ca0, nc0 = cc0, na1 = ca1, nc1 = cc1;
        if (i + 2 < IN_C) {   // constant-folded under full unroll
            na0 = *reinterpret_cast<const float4*>(xb + (size_t)(i + 2) * HW);
            nc0 = *reinterpret_cast<const float4*>(xb + (size_t)(i + 2) * HW + 4);
            na1 = *reinterpret_cast<const float4*>(xb + (size_t)(i + 3) * HW);
            nc1 = *reinterpret_cast<const float4*>(xb + (size_t)(i + 3) * HW + 4);
        }
        const float4 w0 = *reinterpret_cast<const float4*>(&sWT[i * OUT_C + obase]);
        const float4 w1 = *reinterpret_cast<const float4*>(&sWT[i * OUT_C + obase + 4]);
        FMA_TILE(w0, w1, ca0, cc0);
        const float4 u0 = *reinterpret_cast<const float4*>(&sWT[(i + 1) * OUT_C + obase]);
        const float4 u1 = *reinterpret_cast<const float4*>(&sWT[(i + 1) * OUT_C + obase + 4]);
        FMA_TILE(u0, u1, ca1, cc1);
        ca0 = na0; cc0 = nc0; ca1 = na1; cc1 = nc1;
    }
#undef FMA_TILE

    float* ob = out + ((size_t)b * OUT_C + obase) * HW + hw;
    #pragma unroll
    for (int o = 0; o < 8; ++o) {
        const float bv = bias[obase + o];
        float4 r0, r1;
        r0.x = acc[o][0] + bv;  r0.y = acc[o][1] + bv;
        r0.z = acc[o][2] + bv;  r0.w = acc[o][3] + bv;
        r1.x = acc[o][4] + bv;  r1.y = acc[o][5] + bv;
        r1.z = acc[o][6] + bv;  r1.w = acc[o][7] + bv;
        *reinterpret_cast<float4*>(ob + (size_t)o * HW)     = r0;
        *reinterpret_cast<float4*>(ob + (size_t)o * HW + 4) = r1;
    }
}

extern "C" void kernel_launch(void* const* d_in, const int* in_sizes, int n_in,
                              void* d_out, int out_size, void* d_ws, size_t ws_size,
                              hipStream_t stream) {
    const float* x      = (const float*)d_in[0];  // (16,64,128,128)
    const float* style  = (const float*)d_in[1];  // (16,512)
    const float* weight = (const float*)d_in[2];  // (1,64,64,1,1)
    const float* bias   = (const float*)d_in[3];  // (1,64)
    const float* geo_w  = (const float*)d_in[4];  // (64,512)
    const float* geo_b  = (const float*)d_in[5];  // (64)
    float* out = (float*)d_out;

    fused_kernel<<<B_SZ * (HW / HWT), 256, 0, stream>>>(
        x, style, weight, bias, geo_w, geo_b, out);
}